// Round 24
// baseline (136.779 us; speedup 1.0000x reference)
//
#include <hip/hip_runtime.h>

#define BB 4
#define CC 256
#define HH 48
#define WW 48
#define HWHW 2304
#define KK 49
#define RELN 128

// ws float offsets: QB(bf16,swz) | (free) | v f32 | sbuf | WT | KB(bf16,swz) | RB
#define QSZ (BB*CC*HWHW)            // 2359296 floats
#define ATTNOFF (3*QSZ)             // sbuf: [B*H][64][48] taps 0..48
#define SBUF_FLOATS (BB*HH*64*WW)
#define WTOFF (ATTNOFF + SBUF_FLOATS)
#define WT_FLOATS 196608
#define KBOFF (WTOFF + WT_FLOATS)   // KB: 4b*8ck*48h*64row*64u16
#define KB_FLOATS 3145728
#define RBOFF (KBOFF + KB_FLOATS)   // RB: 2rel*4ck*16l*64u16
// XT (bf16 hi/lo of x, pre-swizzled) lives in d_out

typedef short bf16x8 __attribute__((ext_vector_type(8)));
typedef float f32x4 __attribute__((ext_vector_type(4)));

__device__ __forceinline__ void split_bf16(float f, unsigned short& hi, unsigned short& lo)
{
    unsigned u = __float_as_uint(f);
    hi = (unsigned short)(u >> 16);
    float r = f - __uint_as_float(u & 0xFFFF0000u);
    unsigned v = __float_as_uint(r);
    v += 0x7FFFu + ((v >> 16) & 1u);
    lo = (unsigned short)(v >> 16);
}

__device__ __forceinline__ void gload16(const uint4* g, uint4* l)
{
    __builtin_amdgcn_global_load_lds(
        (const __attribute__((address_space(1))) void*)g,
        (__attribute__((address_space(3))) void*)l, 16, 0, 0);
}

// ---- prep: convert x->XT | w->WT | zero KB pad rows | build RB ----
__global__ __launch_bounds__(256) void prep_kernel(
    const float* __restrict__ x,
    const float* __restrict__ wq, const float* __restrict__ wk,
    const float* __restrict__ wvp,
    const float* __restrict__ relx, const float* __restrict__ rely,
    unsigned short* __restrict__ xt, unsigned short* __restrict__ wt,
    float* __restrict__ ws)
{
    __shared__ unsigned short lds[32*520];
    const int bid = blockIdx.x;
    const int t = threadIdx.x;

    if (bid < 288) {                       // convert_x
        const int b = bid / 72;
        const int hw0 = (bid % 72) * 32;
        const int hw = t & 31, cp = t >> 5;
        #pragma unroll 4
        for (int i = 0; i < 32; ++i) {
            int c = i*8 + cp;
            float f = x[((size_t)b*CC + c)*HWHW + hw0 + hw];
            unsigned short hi, lo; split_bf16(f, hi, lo);
            int ch = i*2;
            lds[hw*520 + ((ch       ^ (hw&7))*8) + cp] = hi;
            lds[hw*520 + (((ch + 1) ^ (hw&7))*8) + cp] = lo;
        }
        __syncthreads();
        const int hw2 = t >> 3, u = t & 7;
        uint4* xt4 = (uint4*)xt;
        const size_t rowbase = ((size_t)b*HWHW + hw0 + hw2) * 64;
        #pragma unroll
        for (int j = 0; j < 8; ++j) {
            int chunk = j*8 + u;
            uint4 v = *(const uint4*)&lds[hw2*520 + chunk*8];
            xt4[rowbase + chunk] = v;
        }
        return;
    }
    if (bid < 384) {                       // convert_w
        const int tt = (bid - 288)*256 + t;
        const int m = tt >> 5, kg = tt & 31;
        const float* src = (m < 256) ? wq : (m < 512) ? wk : wvp;
        const float* row = src + (size_t)(m & 255)*256 + kg*8;
        unsigned short h[8], l[8];
        #pragma unroll
        for (int j = 0; j < 8; ++j) split_bf16(row[j], h[j], l[j]);
        uint4 hv, lv;
        hv.x = (unsigned)h[0] | ((unsigned)h[1]<<16); hv.y = (unsigned)h[2] | ((unsigned)h[3]<<16);
        hv.z = (unsigned)h[4] | ((unsigned)h[5]<<16); hv.w = (unsigned)h[6] | ((unsigned)h[7]<<16);
        lv.x = (unsigned)l[0] | ((unsigned)l[1]<<16); lv.y = (unsigned)l[2] | ((unsigned)l[3]<<16);
        lv.z = (unsigned)l[4] | ((unsigned)l[5]<<16); lv.w = (unsigned)l[6] | ((unsigned)l[7]<<16);
        uint4* dstrow = (uint4*)wt + (size_t)m*64;
        const int ks = kg >> 2, s_hi = 2*(kg & 3);
        dstrow[ks*8 + ( s_hi      ^ (m&7))] = hv;
        dstrow[ks*8 + ((s_hi + 1) ^ (m&7))] = lv;
        return;
    }
    if (bid < 576) {                       // zero only KB PAD rows
        uint4* kb4 = (uint4*)(ws + KBOFF);
        const uint4 z = make_uint4(0u,0u,0u,0u);
        int u0 = (bid - 384)*256 + t;
        #pragma unroll
        for (int it = 0; it < 4; ++it) {
            int u = u0 + it*49152;
            int bch = u >> 7, rem = u & 127;
            int r16 = rem >> 3, gr = rem & 7;
            int r = (r16 < 3) ? r16 : 48 + r16;
            kb4[((size_t)bch*64 + r)*8 + gr] = z;
        }
        return;
    }
    {                                       // RB
        unsigned short* rb = (unsigned short*)(ws + RBOFF);
        #pragma unroll
        for (int it = 0; it < 4; ++it) {
            int idx = t + it*256;
            int gi  = idx & 7;
            int l   = (idx >> 3) & 15;
            int ck4 = (idx >> 7) & 3;
            int rel = idx >> 9;
            int isLo = gi >> 2, g4i = gi & 3;
            unsigned short vals[8];
            #pragma unroll
            for (int j = 0; j < 8; ++j) {
                int cl = ck4*32 + g4i*8 + j;
                float f = (l < 7) ? (rel ? rely[cl*7 + l] : relx[cl*7 + l]) : 0.f;
                unsigned short hi, lo; split_bf16(f, hi, lo);
                vals[j] = isLo ? lo : hi;
            }
            int slot = gi ^ (l & 7);
            unsigned short* dst = rb + (((size_t)rel*4 + ck4)*16 + l)*64 + slot*8;
            uint4 pack;
            pack.x = (unsigned)vals[0] | ((unsigned)vals[1]<<16);
            pack.y = (unsigned)vals[2] | ((unsigned)vals[3]<<16);
            pack.z = (unsigned)vals[4] | ((unsigned)vals[5]<<16);
            pack.w = (unsigned)vals[6] | ((unsigned)vals[7]<<16);
            *(uint4*)dst = pack;
        }
    }
}

// ---- Projection GEMM (unchanged: BM=256, counted-vmcnt dbuf) ----
__global__ __launch_bounds__(512) void proj_gemm_kernel(
    const unsigned short* __restrict__ xt,
    const unsigned short* __restrict__ wt,
    float* __restrict__ ws)
{
    __shared__ uint4 smem[2][2560];
    const int m0 = blockIdx.x * 256;
    const int n0 = blockIdx.y * 64;
    const int b = n0 / HWHW;
    const int hwb = n0 % HWHW;
    const int tid = threadIdx.x;
    const int wid = tid >> 6, ln = tid & 63;
    const int wm = wid >> 1, wn = wid & 1;
    const int l15 = ln & 15, g = ln >> 4;

    f32x4 acc[4][2];
    #pragma unroll
    for (int i = 0; i < 4; ++i)
        #pragma unroll
        for (int j = 0; j < 2; ++j) acc[i][j] = (f32x4){0.f,0.f,0.f,0.f};

    const uint4* wt4 = (const uint4*)wt;
    const uint4* xt4 = (const uint4*)xt;
    const int lrow = ln >> 3, lslot = ln & 7;

    #define STAGE(bf, ks)                                                          \
        {                                                                          \
            _Pragma("unroll")                                                      \
            for (int i = 0; i < 4; ++i) {                                          \
                int seg = wid*4 + i;                                               \
                int row = seg*8 + lrow;                                            \
                gload16(wt4 + (size_t)(m0 + row)*64 + (ks)*8 + lslot,              \
                        &smem[bf][seg*64]);                                        \
            }                                                                      \
            {                                                                      \
                int row = wid*8 + lrow;                                            \
                gload16(xt4 + (size_t)(n0 + row)*64 + (ks)*8 + lslot,              \
                        &smem[bf][2048 + wid*64]);                                 \
            }                                                                      \
        }

    STAGE(0, 0);
    #pragma unroll
    for (int ks = 0; ks < 8; ++ks) {
        const int cur = ks & 1;
        if (ks < 7) STAGE(cur ^ 1, ks + 1);
        if (ks < 7) asm volatile("s_waitcnt vmcnt(5)" ::: "memory");
        else        asm volatile("s_waitcnt vmcnt(0)" ::: "memory");
        __builtin_amdgcn_s_barrier();
        __builtin_amdgcn_sched_barrier(0);
        bf16x8 aH[4], aL[4], bH[2], bL[2];
        #pragma unroll
        for (int mt = 0; mt < 4; ++mt) {
            int rA = wm*64 + mt*16 + l15;
            aH[mt] = *(const bf16x8*)&smem[cur][rA*8 + ((2*g)   ^ (rA&7))];
            aL[mt] = *(const bf16x8*)&smem[cur][rA*8 + ((2*g+1) ^ (rA&7))];
        }
        #pragma unroll
        for (int nt = 0; nt < 2; ++nt) {
            int rB = wn*32 + nt*16 + l15;
            bH[nt] = *(const bf16x8*)&smem[cur][2048 + rB*8 + ((2*g)   ^ (rB&7))];
            bL[nt] = *(const bf16x8*)&smem[cur][2048 + rB*8 + ((2*g+1) ^ (rB&7))];
        }
        #pragma unroll
        for (int mt = 0; mt < 4; ++mt)
            #pragma unroll
            for (int nt = 0; nt < 2; ++nt) {
                acc[mt][nt] = __builtin_amdgcn_mfma_f32_16x16x32_bf16(aH[mt], bH[nt], acc[mt][nt], 0, 0, 0);
                acc[mt][nt] = __builtin_amdgcn_mfma_f32_16x16x32_bf16(aH[mt], bL[nt], acc[mt][nt], 0, 0, 0);
                acc[mt][nt] = __builtin_amdgcn_mfma_f32_16x16x32_bf16(aL[mt], bH[nt], acc[mt][nt], 0, 0, 0);
            }
        if (ks < 7) {
            asm volatile("s_waitcnt lgkmcnt(0)" ::: "memory");
            __builtin_amdgcn_s_barrier();
        }
    }
    #undef STAGE

    const int proj = blockIdx.x;
    if (proj == 2) {
        #pragma unroll
        for (int mt = 0; mt < 4; ++mt) {
            int ch4 = wm*16 + mt*4 + g;
            #pragma unroll
            for (int nt = 0; nt < 2; ++nt) {
                int hw = hwb + wn*32 + nt*16 + l15;
                float* dst = ws + (size_t)2*QSZ + (((size_t)b*64 + ch4)*HWHW + hw)*4;
                *(f32x4*)dst = acc[mt][nt];
            }
        }
        return;
    }
    __syncthreads();
    unsigned short* eb = (unsigned short*)&smem[0][0];
    #pragma unroll
    for (int mt = 0; mt < 4; ++mt) {
        const int chb = wm*64 + mt*16 + 4*g;
        const int ck = chb >> 5;
        const int p = chb & 31, g8 = p >> 3, half = (p >> 2) & 1;
        #pragma unroll
        for (int nt = 0; nt < 2; ++nt) {
            const int hwl = wn*32 + nt*16 + l15;
            const int w = (hwb + hwl) % 48;
            const int key = (proj == 0 ? w : w + 3) & 7;
            f32x4 v = acc[mt][nt];
            unsigned short h0,h1,h2,h3,q0,q1,q2,q3;
            split_bf16(v[0],h0,q0); split_bf16(v[1],h1,q1);
            split_bf16(v[2],h2,q2); split_bf16(v[3],h3,q3);
            uint2 hv, lv;
            hv.x = (unsigned)h0 | ((unsigned)h1<<16); hv.y = (unsigned)h2 | ((unsigned)h3<<16);
            lv.x = (unsigned)q0 | ((unsigned)q1<<16); lv.y = (unsigned)q2 | ((unsigned)q3<<16);
            const int base = (ck*64 + hwl)*64;
            *(uint2*)(eb + base + ((g8 ^ key)*8 + half*4))     = hv;
            *(uint2*)(eb + base + (((g8+4) ^ key)*8 + half*4)) = lv;
        }
    }
    __syncthreads();
    if (proj == 0) {
        const uint4* src = (const uint4*)eb;
        uint4* qb4 = (uint4*)ws;
        #pragma unroll
        for (int ck = 0; ck < 8; ++ck) {
            uint4* dst = qb4 + (((size_t)b*8 + ck)*HWHW + hwb)*8;
            dst[tid] = src[ck*512 + tid];
        }
    } else {
        uint4* kb4 = (uint4*)(ws + KBOFF);
        const uint4* src = (const uint4*)eb;
        #pragma unroll
        for (int it = 0; it < 8; ++it) {
            int u = it*512 + tid;
            int row = u >> 3, gr = u & 7;
            int ck = row >> 6, hwl = row & 63;
            int hw2 = hwb + hwl, h2 = hw2/48, w2 = hw2%48;
            kb4[((((size_t)b*8 + ck)*48 + h2)*64 + (w2+3))*8 + gr] = src[u];
        }
    }
}

// ---- scores2: banded MFMA, double-buffered counted-vmcnt (R20 exact, reverted) ----
__global__ __launch_bounds__(512) void scores2_kernel(float* __restrict__ ws)
{
    __shared__ unsigned short sAll[2][4096*8];   // 2 x 64 KB
    __shared__ float sc[63][48];

    const int bid = blockIdx.x;
    const int b = bid / 48, h = bid % 48;
    const int tid = threadIdx.x;
    const int wv = tid >> 6, ln = tid & 63;
    const int l15 = ln & 15, g4 = ln >> 4;
    const int key = l15 & 7;

    const unsigned short* QB = (const unsigned short*)ws;
    const unsigned short* KB = (const unsigned short*)(ws + KBOFF);
    const unsigned short* RB = (const unsigned short*)(ws + RBOFF);

    for (int u = tid; u < 63*48; u += 512) ((float*)sc)[u] = 0.f;

    const int dk = wv;
    const int hp = h + dk - 3;
    const bool dok = (wv < 7) && (hp >= 0) && (hp < 48);

    f32x4 acc[6], qx[3], qy[3];
    #pragma unroll
    for (int i = 0; i < 6; ++i) acc[i] = (f32x4){0.f,0.f,0.f,0.f};
    #pragma unroll
    for (int i = 0; i < 3; ++i) { qx[i] = (f32x4){0.f,0.f,0.f,0.f}; qy[i] = (f32x4){0.f,0.f,0.f,0.f}; }

    #define SSTAGE(bf, ck)                                                         \
        {                                                                          \
            _Pragma("unroll")                                                      \
            for (int e = 0; e < 8; ++e) {                                          \
                const int I = wv*8 + e;                                            \
                uint4* dst = (uint4*)sAll[bf] + I*64;                              \
                if (I < 6) {                                                       \
                    int unit = I*64 + ln; int row = unit >> 3, gr = unit & 7;      \
                    gload16((const uint4*)QB                                       \
                        + ((((size_t)b*8 + (ck))*48 + h)*48 + row)*8 + gr, dst);   \
                } else if (I < 62) {                                               \
                    int uk = (I-6)*64 + ln;                                        \
                    int kri = uk >> 9;                                             \
                    int wi = uk & 511; int row = wi >> 3, gr = wi & 7;             \
                    int kh = h + kri - 3;                                          \
                    int khc = kh < 0 ? 0 : (kh > 47 ? 47 : kh);                    \
                    gload16((const uint4*)KB                                       \
                        + ((((size_t)b*8 + (ck))*48 + khc)*64 + row)*8 + gr, dst); \
                } else {                                                           \
                    int ur = (I-62)*64 + ln; int row = ur >> 3, gr = ur & 7;       \
                    int rel = (ck) >> 2, c4 = (ck) & 3;                            \
                    gload16((const uint4*)RB                                       \
                        + (((size_t)rel*4 + c4)*16 + row)*8 + gr, dst);            \
                }                                                                  \
            }                                                                      \
        }

    SSTAGE(0, 0);
    for (int ck = 0; ck < 8; ++ck) {
        const int cur = ck & 1;
        if (ck < 7) SSTAGE(cur ^ 1, ck + 1);
        if (ck < 7) asm volatile("s_waitcnt vmcnt(8)" ::: "memory");
        else        asm volatile("s_waitcnt vmcnt(0)" ::: "memory");
        __builtin_amdgcn_s_barrier();
        __builtin_amdgcn_sched_barrier(0);

        const unsigned short* sQ = sAll[cur];
        const unsigned short* sK = sAll[cur] + 384*8;
        const unsigned short* sR = sAll[cur] + 3968*8;

        bf16x8 AH[3], AL[3];
        #pragma unroll
        for (int i = 0; i < 3; ++i) {
            const unsigned short* qr = sQ + (16*i + l15)*64;
            AH[i] = *(const bf16x8*)(qr + ((g4       ^ key)*8));
            AL[i] = *(const bf16x8*)(qr + (((g4 + 4) ^ key)*8));
        }

        if (wv < 7) {
            if (dok) {
                const unsigned short* kbase = sK + dk*4096;
                bf16x8 BH[4], BL[4];
                #pragma unroll
                for (int j = 0; j < 4; ++j) {
                    const unsigned short* kr = kbase + (j*16 + l15)*64;
                    BH[j] = *(const bf16x8*)(kr + ((g4       ^ key)*8));
                    BL[j] = *(const bf16x8*)(kr + (((g4 + 4) ^ key)*8));
                }
                #pragma unroll
                for (int i = 0; i < 3; ++i) {
                    acc[i*2]   = __builtin_amdgcn_mfma_f32_16x16x32_bf16(AH[i], BH[i],   acc[i*2],   0,0,0);
                    acc[i*2]   = __builtin_amdgcn_mfma_f32_16x16x32_bf16(AH[i], BL[i],   acc[i*2],   0,0,0);
                    acc[i*2]   = __builtin_amdgcn_mfma_f32_16x16x32_bf16(AL[i], BH[i],   acc[i*2],   0,0,0);
                    acc[i*2+1] = __builtin_amdgcn_mfma_f32_16x16x32_bf16(AH[i], BH[i+1], acc[i*2+1], 0,0,0);
                    acc[i*2+1] = __builtin_amdgcn_mfma_f32_16x16x32_bf16(AH[i], BL[i+1], acc[i*2+1], 0,0,0);
                    acc[i*2+1] = __builtin_amdgcn_mfma_f32_16x16x32_bf16(AL[i], BH[i+1], acc[i*2+1], 0,0,0);
                }
            }
        } else {
            const unsigned short* rr = sR + l15*64;
            bf16x8 RH = *(const bf16x8*)(rr + ((g4       ^ key)*8));
            bf16x8 RL = *(const bf16x8*)(rr + (((g4 + 4) ^ key)*8));
            if (ck < 4) {
                #pragma unroll
                for (int i = 0; i < 3; ++i) {
                    qx[i] = __builtin_amdgcn_mfma_f32_16x16x32_bf16(AH[i], RH, qx[i], 0,0,0);
                    qx[i] = __builtin_amdgcn_mfma_f32_16x16x32_bf16(AH[i], RL, qx[i], 0,0,0);
                    qx[i] = __builtin_amdgcn_mfma_f32_16x16x32_bf16(AL[i], RH, qx[i], 0,0,0);
                }
            } else {
                #pragma unroll
                for (int i = 0; i < 3; ++i) {
                    qy[i] = __builtin_amdgcn_mfma_f32_16x16x32_bf16(AH[i], RH, qy[i], 0,0,0);
                    qy[i] = __builtin_amdgcn_mfma_f32_16x16x32_bf16(AH[i], RL, qy[i], 0,0,0);
                    qy[i] = __builtin_amdgcn_mfma_f32_16x16x32_bf16(AL[i], RH, qy[i], 0,0,0);
                }
            }
        }
        if (ck < 7) {
            asm volatile("s_waitcnt lgkmcnt(0)" ::: "memory");
            __builtin_amdgcn_s_barrier();
        }
    }
    #undef SSTAGE

    const int n = l15;
    if (wv < 7) {
        if (dok) {
            #pragma unroll
            for (int i = 0; i < 3; ++i)
                #pragma unroll
                for (int a = 0; a < 2; ++a) {
                    f32x4 A = acc[i*2+a];
                    #pragma unroll
                    for (int r = 0; r < 4; ++r) {
                        int m = 4*g4 + r;
                        int dl = n - m + a*16;
                        if (dl >= 0 && dl < 7)
                            sc[dk*7 + dl][16*i + m] = A[r];
                    }
                }
        }
    } else {
        if (n < 7) {
            #pragma unroll
            for (int i = 0; i < 3; ++i)
                #pragma unroll
                for (int r = 0; r < 4; ++r) {
                    sc[49 + n][16*i + 4*g4 + r] = qx[i][r];
                    sc[56 + n][16*i + 4*g4 + r] = qy[i][r];
                }
        }
    }
    __syncthreads();

    if (tid < 48) {
        const int w = tid;
        float tot[KK], rx[7], ry[7];
        #pragma unroll
        for (int i = 0; i < KK; ++i) tot[i] = sc[i][w];
        #pragma unroll
        for (int l = 0; l < 7; ++l) { rx[l] = sc[49+l][w]; ry[l] = sc[56+l][w]; }
        float mx = -1e30f;
        #pragma unroll
        for (int dk2 = 0; dk2 < 7; ++dk2)
            #pragma unroll
            for (int dl = 0; dl < 7; ++dl) {
                tot[dk2*7+dl] += ry[dk2] + rx[dl];
                mx = fmaxf(mx, tot[dk2*7+dl]);
            }
        float sum = 0.f;
        #pragma unroll
        for (int i = 0; i < KK; ++i) { float e = __expf(tot[i]-mx); tot[i]=e; sum += e; }
        float inv = 1.f/sum;
        float* base = ws + ATTNOFF + ((size_t)(b*HH + h)*64)*WW + w;
        #pragma unroll
        for (int i = 0; i < KK; ++i) base[(size_t)i*WW] = tot[i]*inv;
    }
}

// ---- PV + bias (unchanged) ----
__global__ __launch_bounds__(128) void pv_kernel(
    const float* __restrict__ bias,
    const float* __restrict__ ws,
    float* __restrict__ out)
{
    const float* vbuf = ws + (size_t)2*QSZ;
    const float* attn = ws + ATTNOFF;

    const int bid = blockIdx.x;
    const int pxt = bid % 18;
    const int pgq = (bid / 18) % 16;
    const int b   = bid / (18*16);

    const int tid = threadIdx.x;
    const int pxg = tid & 31;
    const int pg  = pgq*4 + (tid >> 5);

    const int hw0 = pxt*128 + pxg*4;
    const int w0 = hw0 % WW;
    const int h0 = hw0 / WW;

    const float* vb = vbuf + ((size_t)b*64 + pg)*HWHW*4;
    const float* ab = attn + ((size_t)(b*HH + h0)*64)*WW;

    const float4 b4 = *(const float4*)(bias + pg*4);
    f32x4 bias4 = (f32x4){b4.x, b4.y, b4.z, b4.w};
    f32x4 acc[4];
    #pragma unroll
    for (int p = 0; p < 4; ++p) acc[p] = bias4;

    #pragma unroll
    for (int dk = 0; dk < 7; ++dk) {
        const int gr = h0 + dk - 3;
        const bool rok = (gr >= 0 && gr < HH);
        f32x4 vrow[10];
        #pragma unroll
        for (int jj = 0; jj < 10; ++jj) {
            const int gc = w0 - 3 + jj;
            vrow[jj] = (rok && gc >= 0 && gc < WW)
                ? *(const f32x4*)(vb + ((size_t)gr*WW + gc)*4)
                : (f32x4){0.f,0.f,0.f,0.f};
        }
        const float* arow = ab + (size_t)(dk*7)*WW + w0;
        #pragma unroll
        for (int dl = 0; dl < 7; ++dl) {
            const float4 av = *(const float4*)(arow + (size_t)dl*WW);
            acc[0] += vrow[dl+0] * av.x;
            acc[1] += vrow[dl+1] * av.y;
            acc[2] += vrow[dl+2] * av.z;
            acc[3] += vrow[dl+3] * av.w;
        }
    }
    #pragma unroll
    for (int c = 0; c < 4; ++c) {
        float4 o;
        o.x = acc[0][c]; o.y = acc[1][c]; o.z = acc[2][c]; o.w = acc[3][c];
        *(float4*)(out + ((size_t)b*CC + pg*4 + c)*HWHW + hw0) = o;
    }
}

extern "C" void kernel_launch(void* const* d_in, const int* in_sizes, int n_in,
                              void* d_out, int out_size, void* d_ws, size_t ws_size,
                              hipStream_t stream) {
    const float* x    = (const float*)d_in[0];
    const float* wq   = (const float*)d_in[1];
    const float* wk   = (const float*)d_in[2];
    const float* wv   = (const float*)d_in[3];
    const float* bias = (const float*)d_in[4];
    const float* relx = (const float*)d_in[5];
    const float* rely = (const float*)d_in[6];
    float* ws  = (float*)d_ws;
    float* out = (float*)d_out;
    unsigned short* xt = (unsigned short*)d_out;
    unsigned short* wt = (unsigned short*)(ws + WTOFF);

    prep_kernel<<<dim3(577), dim3(256), 0, stream>>>(x, wq, wk, wv, relx, rely, xt, wt, ws);
    proj_gemm_kernel<<<dim3(3, 144), dim3(512), 0, stream>>>(xt, wt, ws);
    scores2_kernel<<<dim3(BB*HH), dim3(512), 0, stream>>>(ws);
    // MEASUREMENT ROUND: pv launched 4x (idempotent: reads ws, writes out).
    // T(pv) = (dur - 72.4)/3.
    pv_kernel<<<dim3(BB*16*18), dim3(128), 0, stream>>>(bias, ws, out);
    pv_kernel<<<dim3(BB*16*18), dim3(128), 0, stream>>>(bias, ws, out);
    pv_kernel<<<dim3(BB*16*18), dim3(128), 0, stream>>>(bias, ws, out);
    pv_kernel<<<dim3(BB*16*18), dim3(128), 0, stream>>>(bias, ws, out);
}

// Round 25
// 64.463 us; speedup vs baseline: 2.1218x; 2.1218x over previous
//
#include <hip/hip_runtime.h>

#define BB 4
#define CC 256
#define HH 48
#define WW 48
#define HWHW 2304
#define KK 49
#define RELN 128

// ws float offsets: QB(bf16,swz) | (free) | v f32 | sbuf | WT | KB(bf16,swz) | RB
#define QSZ (BB*CC*HWHW)            // 2359296 floats
#define ATTNOFF (3*QSZ)             // sbuf: [B*H][64][48] taps 0..48
#define SBUF_FLOATS (BB*HH*64*WW)
#define WTOFF (ATTNOFF + SBUF_FLOATS)
#define WT_FLOATS 196608
#define KBOFF (WTOFF + WT_FLOATS)   // KB: 4b*8ck*48h*64row*64u16
#define KB_FLOATS 3145728
#define RBOFF (KBOFF + KB_FLOATS)   // RB: 2rel*4ck*16l*64u16
// XT (bf16 hi/lo of x, pre-swizzled) lives in d_out

typedef short bf16x8 __attribute__((ext_vector_type(8)));
typedef float f32x4 __attribute__((ext_vector_type(4)));

__device__ __forceinline__ void split_bf16(float f, unsigned short& hi, unsigned short& lo)
{
    unsigned u = __float_as_uint(f);
    hi = (unsigned short)(u >> 16);
    float r = f - __uint_as_float(u & 0xFFFF0000u);
    unsigned v = __float_as_uint(r);
    v += 0x7FFFu + ((v >> 16) & 1u);
    lo = (unsigned short)(v >> 16);
}

__device__ __forceinline__ void gload16(const uint4* g, uint4* l)
{
    __builtin_amdgcn_global_load_lds(
        (const __attribute__((address_space(1))) void*)g,
        (__attribute__((address_space(3))) void*)l, 16, 0, 0);
}

// ---- prep: convert x->XT | w->WT | zero KB pad rows | build RB ----
__global__ __launch_bounds__(256) void prep_kernel(
    const float* __restrict__ x,
    const float* __restrict__ wq, const float* __restrict__ wk,
    const float* __restrict__ wvp,
    const float* __restrict__ relx, const float* __restrict__ rely,
    unsigned short* __restrict__ xt, unsigned short* __restrict__ wt,
    float* __restrict__ ws)
{
    __shared__ unsigned short lds[32*520];
    const int bid = blockIdx.x;
    const int t = threadIdx.x;

    if (bid < 288) {                       // convert_x
        const int b = bid / 72;
        const int hw0 = (bid % 72) * 32;
        const int hw = t & 31, cp = t >> 5;
        #pragma unroll 4
        for (int i = 0; i < 32; ++i) {
            int c = i*8 + cp;
            float f = x[((size_t)b*CC + c)*HWHW + hw0 + hw];
            unsigned short hi, lo; split_bf16(f, hi, lo);
            int ch = i*2;
            lds[hw*520 + ((ch       ^ (hw&7))*8) + cp] = hi;
            lds[hw*520 + (((ch + 1) ^ (hw&7))*8) + cp] = lo;
        }
        __syncthreads();
        const int hw2 = t >> 3, u = t & 7;
        uint4* xt4 = (uint4*)xt;
        const size_t rowbase = ((size_t)b*HWHW + hw0 + hw2) * 64;
        #pragma unroll
        for (int j = 0; j < 8; ++j) {
            int chunk = j*8 + u;
            uint4 v = *(const uint4*)&lds[hw2*520 + chunk*8];
            xt4[rowbase + chunk] = v;
        }
        return;
    }
    if (bid < 384) {                       // convert_w
        const int tt = (bid - 288)*256 + t;
        const int m = tt >> 5, kg = tt & 31;
        const float* src = (m < 256) ? wq : (m < 512) ? wk : wvp;
        const float* row = src + (size_t)(m & 255)*256 + kg*8;
        unsigned short h[8], l[8];
        #pragma unroll
        for (int j = 0; j < 8; ++j) split_bf16(row[j], h[j], l[j]);
        uint4 hv, lv;
        hv.x = (unsigned)h[0] | ((unsigned)h[1]<<16); hv.y = (unsigned)h[2] | ((unsigned)h[3]<<16);
        hv.z = (unsigned)h[4] | ((unsigned)h[5]<<16); hv.w = (unsigned)h[6] | ((unsigned)h[7]<<16);
        lv.x = (unsigned)l[0] | ((unsigned)l[1]<<16); lv.y = (unsigned)l[2] | ((unsigned)l[3]<<16);
        lv.z = (unsigned)l[4] | ((unsigned)l[5]<<16); lv.w = (unsigned)l[6] | ((unsigned)l[7]<<16);
        uint4* dstrow = (uint4*)wt + (size_t)m*64;
        const int ks = kg >> 2, s_hi = 2*(kg & 3);
        dstrow[ks*8 + ( s_hi      ^ (m&7))] = hv;
        dstrow[ks*8 + ((s_hi + 1) ^ (m&7))] = lv;
        return;
    }
    if (bid < 576) {                       // zero only KB PAD rows
        uint4* kb4 = (uint4*)(ws + KBOFF);
        const uint4 z = make_uint4(0u,0u,0u,0u);
        int u0 = (bid - 384)*256 + t;
        #pragma unroll
        for (int it = 0; it < 4; ++it) {
            int u = u0 + it*49152;
            int bch = u >> 7, rem = u & 127;
            int r16 = rem >> 3, gr = rem & 7;
            int r = (r16 < 3) ? r16 : 48 + r16;
            kb4[((size_t)bch*64 + r)*8 + gr] = z;
        }
        return;
    }
    {                                       // RB
        unsigned short* rb = (unsigned short*)(ws + RBOFF);
        #pragma unroll
        for (int it = 0; it < 4; ++it) {
            int idx = t + it*256;
            int gi  = idx & 7;
            int l   = (idx >> 3) & 15;
            int ck4 = (idx >> 7) & 3;
            int rel = idx >> 9;
            int isLo = gi >> 2, g4i = gi & 3;
            unsigned short vals[8];
            #pragma unroll
            for (int j = 0; j < 8; ++j) {
                int cl = ck4*32 + g4i*8 + j;
                float f = (l < 7) ? (rel ? rely[cl*7 + l] : relx[cl*7 + l]) : 0.f;
                unsigned short hi, lo; split_bf16(f, hi, lo);
                vals[j] = isLo ? lo : hi;
            }
            int slot = gi ^ (l & 7);
            unsigned short* dst = rb + (((size_t)rel*4 + ck4)*16 + l)*64 + slot*8;
            uint4 pack;
            pack.x = (unsigned)vals[0] | ((unsigned)vals[1]<<16);
            pack.y = (unsigned)vals[2] | ((unsigned)vals[3]<<16);
            pack.z = (unsigned)vals[4] | ((unsigned)vals[5]<<16);
            pack.w = (unsigned)vals[6] | ((unsigned)vals[7]<<16);
            *(uint4*)dst = pack;
        }
    }
}

// ---- Projection GEMM (unchanged: BM=256, counted-vmcnt dbuf) ----
__global__ __launch_bounds__(512) void proj_gemm_kernel(
    const unsigned short* __restrict__ xt,
    const unsigned short* __restrict__ wt,
    float* __restrict__ ws)
{
    __shared__ uint4 smem[2][2560];
    const int m0 = blockIdx.x * 256;
    const int n0 = blockIdx.y * 64;
    const int b = n0 / HWHW;
    const int hwb = n0 % HWHW;
    const int tid = threadIdx.x;
    const int wid = tid >> 6, ln = tid & 63;
    const int wm = wid >> 1, wn = wid & 1;
    const int l15 = ln & 15, g = ln >> 4;

    f32x4 acc[4][2];
    #pragma unroll
    for (int i = 0; i < 4; ++i)
        #pragma unroll
        for (int j = 0; j < 2; ++j) acc[i][j] = (f32x4){0.f,0.f,0.f,0.f};

    const uint4* wt4 = (const uint4*)wt;
    const uint4* xt4 = (const uint4*)xt;
    const int lrow = ln >> 3, lslot = ln & 7;

    #define STAGE(bf, ks)                                                          \
        {                                                                          \
            _Pragma("unroll")                                                      \
            for (int i = 0; i < 4; ++i) {                                          \
                int seg = wid*4 + i;                                               \
                int row = seg*8 + lrow;                                            \
                gload16(wt4 + (size_t)(m0 + row)*64 + (ks)*8 + lslot,              \
                        &smem[bf][seg*64]);                                        \
            }                                                                      \
            {                                                                      \
                int row = wid*8 + lrow;                                            \
                gload16(xt4 + (size_t)(n0 + row)*64 + (ks)*8 + lslot,              \
                        &smem[bf][2048 + wid*64]);                                 \
            }                                                                      \
        }

    STAGE(0, 0);
    #pragma unroll
    for (int ks = 0; ks < 8; ++ks) {
        const int cur = ks & 1;
        if (ks < 7) STAGE(cur ^ 1, ks + 1);
        if (ks < 7) asm volatile("s_waitcnt vmcnt(5)" ::: "memory");
        else        asm volatile("s_waitcnt vmcnt(0)" ::: "memory");
        __builtin_amdgcn_s_barrier();
        __builtin_amdgcn_sched_barrier(0);
        bf16x8 aH[4], aL[4], bH[2], bL[2];
        #pragma unroll
        for (int mt = 0; mt < 4; ++mt) {
            int rA = wm*64 + mt*16 + l15;
            aH[mt] = *(const bf16x8*)&smem[cur][rA*8 + ((2*g)   ^ (rA&7))];
            aL[mt] = *(const bf16x8*)&smem[cur][rA*8 + ((2*g+1) ^ (rA&7))];
        }
        #pragma unroll
        for (int nt = 0; nt < 2; ++nt) {
            int rB = wn*32 + nt*16 + l15;
            bH[nt] = *(const bf16x8*)&smem[cur][2048 + rB*8 + ((2*g)   ^ (rB&7))];
            bL[nt] = *(const bf16x8*)&smem[cur][2048 + rB*8 + ((2*g+1) ^ (rB&7))];
        }
        #pragma unroll
        for (int mt = 0; mt < 4; ++mt)
            #pragma unroll
            for (int nt = 0; nt < 2; ++nt) {
                acc[mt][nt] = __builtin_amdgcn_mfma_f32_16x16x32_bf16(aH[mt], bH[nt], acc[mt][nt], 0, 0, 0);
                acc[mt][nt] = __builtin_amdgcn_mfma_f32_16x16x32_bf16(aH[mt], bL[nt], acc[mt][nt], 0, 0, 0);
                acc[mt][nt] = __builtin_amdgcn_mfma_f32_16x16x32_bf16(aL[mt], bH[nt], acc[mt][nt], 0, 0, 0);
            }
        if (ks < 7) {
            asm volatile("s_waitcnt lgkmcnt(0)" ::: "memory");
            __builtin_amdgcn_s_barrier();
        }
    }
    #undef STAGE

    const int proj = blockIdx.x;
    if (proj == 2) {
        #pragma unroll
        for (int mt = 0; mt < 4; ++mt) {
            int ch4 = wm*16 + mt*4 + g;
            #pragma unroll
            for (int nt = 0; nt < 2; ++nt) {
                int hw = hwb + wn*32 + nt*16 + l15;
                float* dst = ws + (size_t)2*QSZ + (((size_t)b*64 + ch4)*HWHW + hw)*4;
                *(f32x4*)dst = acc[mt][nt];
            }
        }
        return;
    }
    __syncthreads();
    unsigned short* eb = (unsigned short*)&smem[0][0];
    #pragma unroll
    for (int mt = 0; mt < 4; ++mt) {
        const int chb = wm*64 + mt*16 + 4*g;
        const int ck = chb >> 5;
        const int p = chb & 31, g8 = p >> 3, half = (p >> 2) & 1;
        #pragma unroll
        for (int nt = 0; nt < 2; ++nt) {
            const int hwl = wn*32 + nt*16 + l15;
            const int w = (hwb + hwl) % 48;
            const int key = (proj == 0 ? w : w + 3) & 7;
            f32x4 v = acc[mt][nt];
            unsigned short h0,h1,h2,h3,q0,q1,q2,q3;
            split_bf16(v[0],h0,q0); split_bf16(v[1],h1,q1);
            split_bf16(v[2],h2,q2); split_bf16(v[3],h3,q3);
            uint2 hv, lv;
            hv.x = (unsigned)h0 | ((unsigned)h1<<16); hv.y = (unsigned)h2 | ((unsigned)h3<<16);
            lv.x = (unsigned)q0 | ((unsigned)q1<<16); lv.y = (unsigned)q2 | ((unsigned)q3<<16);
            const int base = (ck*64 + hwl)*64;
            *(uint2*)(eb + base + ((g8 ^ key)*8 + half*4))     = hv;
            *(uint2*)(eb + base + (((g8+4) ^ key)*8 + half*4)) = lv;
        }
    }
    __syncthreads();
    if (proj == 0) {
        const uint4* src = (const uint4*)eb;
        uint4* qb4 = (uint4*)ws;
        #pragma unroll
        for (int ck = 0; ck < 8; ++ck) {
            uint4* dst = qb4 + (((size_t)b*8 + ck)*HWHW + hwb)*8;
            dst[tid] = src[ck*512 + tid];
        }
    } else {
        uint4* kb4 = (uint4*)(ws + KBOFF);
        const uint4* src = (const uint4*)eb;
        #pragma unroll
        for (int it = 0; it < 8; ++it) {
            int u = it*512 + tid;
            int row = u >> 3, gr = u & 7;
            int ck = row >> 6, hwl = row & 63;
            int hw2 = hwb + hwl, h2 = hw2/48, w2 = hw2%48;
            kb4[((((size_t)b*8 + ck)*48 + h2)*64 + (w2+3))*8 + gr] = src[u];
        }
    }
}

// ---- scores2: banded MFMA, double-buffered counted-vmcnt (unchanged R20) ----
__global__ __launch_bounds__(512) void scores2_kernel(float* __restrict__ ws)
{
    __shared__ unsigned short sAll[2][4096*8];   // 2 x 64 KB
    __shared__ float sc[63][48];

    const int bid = blockIdx.x;
    const int b = bid / 48, h = bid % 48;
    const int tid = threadIdx.x;
    const int wv = tid >> 6, ln = tid & 63;
    const int l15 = ln & 15, g4 = ln >> 4;
    const int key = l15 & 7;

    const unsigned short* QB = (const unsigned short*)ws;
    const unsigned short* KB = (const unsigned short*)(ws + KBOFF);
    const unsigned short* RB = (const unsigned short*)(ws + RBOFF);

    for (int u = tid; u < 63*48; u += 512) ((float*)sc)[u] = 0.f;

    const int dk = wv;
    const int hp = h + dk - 3;
    const bool dok = (wv < 7) && (hp >= 0) && (hp < 48);

    f32x4 acc[6], qx[3], qy[3];
    #pragma unroll
    for (int i = 0; i < 6; ++i) acc[i] = (f32x4){0.f,0.f,0.f,0.f};
    #pragma unroll
    for (int i = 0; i < 3; ++i) { qx[i] = (f32x4){0.f,0.f,0.f,0.f}; qy[i] = (f32x4){0.f,0.f,0.f,0.f}; }

    #define SSTAGE(bf, ck)                                                         \
        {                                                                          \
            _Pragma("unroll")                                                      \
            for (int e = 0; e < 8; ++e) {                                          \
                const int I = wv*8 + e;                                            \
                uint4* dst = (uint4*)sAll[bf] + I*64;                              \
                if (I < 6) {                                                       \
                    int unit = I*64 + ln; int row = unit >> 3, gr = unit & 7;      \
                    gload16((const uint4*)QB                                       \
                        + ((((size_t)b*8 + (ck))*48 + h)*48 + row)*8 + gr, dst);   \
                } else if (I < 62) {                                               \
                    int uk = (I-6)*64 + ln;                                        \
                    int kri = uk >> 9;                                             \
                    int wi = uk & 511; int row = wi >> 3, gr = wi & 7;             \
                    int kh = h + kri - 3;                                          \
                    int khc = kh < 0 ? 0 : (kh > 47 ? 47 : kh);                    \
                    gload16((const uint4*)KB                                       \
                        + ((((size_t)b*8 + (ck))*48 + khc)*64 + row)*8 + gr, dst); \
                } else {                                                           \
                    int ur = (I-62)*64 + ln; int row = ur >> 3, gr = ur & 7;       \
                    int rel = (ck) >> 2, c4 = (ck) & 3;                            \
                    gload16((const uint4*)RB                                       \
                        + (((size_t)rel*4 + c4)*16 + row)*8 + gr, dst);            \
                }                                                                  \
            }                                                                      \
        }

    SSTAGE(0, 0);
    for (int ck = 0; ck < 8; ++ck) {
        const int cur = ck & 1;
        if (ck < 7) SSTAGE(cur ^ 1, ck + 1);
        if (ck < 7) asm volatile("s_waitcnt vmcnt(8)" ::: "memory");
        else        asm volatile("s_waitcnt vmcnt(0)" ::: "memory");
        __builtin_amdgcn_s_barrier();
        __builtin_amdgcn_sched_barrier(0);

        const unsigned short* sQ = sAll[cur];
        const unsigned short* sK = sAll[cur] + 384*8;
        const unsigned short* sR = sAll[cur] + 3968*8;

        bf16x8 AH[3], AL[3];
        #pragma unroll
        for (int i = 0; i < 3; ++i) {
            const unsigned short* qr = sQ + (16*i + l15)*64;
            AH[i] = *(const bf16x8*)(qr + ((g4       ^ key)*8));
            AL[i] = *(const bf16x8*)(qr + (((g4 + 4) ^ key)*8));
        }

        if (wv < 7) {
            if (dok) {
                const unsigned short* kbase = sK + dk*4096;
                bf16x8 BH[4], BL[4];
                #pragma unroll
                for (int j = 0; j < 4; ++j) {
                    const unsigned short* kr = kbase + (j*16 + l15)*64;
                    BH[j] = *(const bf16x8*)(kr + ((g4       ^ key)*8));
                    BL[j] = *(const bf16x8*)(kr + (((g4 + 4) ^ key)*8));
                }
                #pragma unroll
                for (int i = 0; i < 3; ++i) {
                    acc[i*2]   = __builtin_amdgcn_mfma_f32_16x16x32_bf16(AH[i], BH[i],   acc[i*2],   0,0,0);
                    acc[i*2]   = __builtin_amdgcn_mfma_f32_16x16x32_bf16(AH[i], BL[i],   acc[i*2],   0,0,0);
                    acc[i*2]   = __builtin_amdgcn_mfma_f32_16x16x32_bf16(AL[i], BH[i],   acc[i*2],   0,0,0);
                    acc[i*2+1] = __builtin_amdgcn_mfma_f32_16x16x32_bf16(AH[i], BH[i+1], acc[i*2+1], 0,0,0);
                    acc[i*2+1] = __builtin_amdgcn_mfma_f32_16x16x32_bf16(AH[i], BL[i+1], acc[i*2+1], 0,0,0);
                    acc[i*2+1] = __builtin_amdgcn_mfma_f32_16x16x32_bf16(AL[i], BH[i+1], acc[i*2+1], 0,0,0);
                }
            }
        } else {
            const unsigned short* rr = sR + l15*64;
            bf16x8 RH = *(const bf16x8*)(rr + ((g4       ^ key)*8));
            bf16x8 RL = *(const bf16x8*)(rr + (((g4 + 4) ^ key)*8));
            if (ck < 4) {
                #pragma unroll
                for (int i = 0; i < 3; ++i) {
                    qx[i] = __builtin_amdgcn_mfma_f32_16x16x32_bf16(AH[i], RH, qx[i], 0,0,0);
                    qx[i] = __builtin_amdgcn_mfma_f32_16x16x32_bf16(AH[i], RL, qx[i], 0,0,0);
                    qx[i] = __builtin_amdgcn_mfma_f32_16x16x32_bf16(AL[i], RH, qx[i], 0,0,0);
                }
            } else {
                #pragma unroll
                for (int i = 0; i < 3; ++i) {
                    qy[i] = __builtin_amdgcn_mfma_f32_16x16x32_bf16(AH[i], RH, qy[i], 0,0,0);
                    qy[i] = __builtin_amdgcn_mfma_f32_16x16x32_bf16(AH[i], RL, qy[i], 0,0,0);
                    qy[i] = __builtin_amdgcn_mfma_f32_16x16x32_bf16(AL[i], RH, qy[i], 0,0,0);
                }
            }
        }
        if (ck < 7) {
            asm volatile("s_waitcnt lgkmcnt(0)" ::: "memory");
            __builtin_amdgcn_s_barrier();
        }
    }
    #undef SSTAGE

    const int n = l15;
    if (wv < 7) {
        if (dok) {
            #pragma unroll
            for (int i = 0; i < 3; ++i)
                #pragma unroll
                for (int a = 0; a < 2; ++a) {
                    f32x4 A = acc[i*2+a];
                    #pragma unroll
                    for (int r = 0; r < 4; ++r) {
                        int m = 4*g4 + r;
                        int dl = n - m + a*16;
                        if (dl >= 0 && dl < 7)
                            sc[dk*7 + dl][16*i + m] = A[r];
                    }
                }
        }
    } else {
        if (n < 7) {
            #pragma unroll
            for (int i = 0; i < 3; ++i)
                #pragma unroll
                for (int r = 0; r < 4; ++r) {
                    sc[49 + n][16*i + 4*g4 + r] = qx[i][r];
                    sc[56 + n][16*i + 4*g4 + r] = qy[i][r];
                }
        }
    }
    __syncthreads();

    if (tid < 48) {
        const int w = tid;
        float tot[KK], rx[7], ry[7];
        #pragma unroll
        for (int i = 0; i < KK; ++i) tot[i] = sc[i][w];
        #pragma unroll
        for (int l = 0; l < 7; ++l) { rx[l] = sc[49+l][w]; ry[l] = sc[56+l][w]; }
        float mx = -1e30f;
        #pragma unroll
        for (int dk2 = 0; dk2 < 7; ++dk2)
            #pragma unroll
            for (int dl = 0; dl < 7; ++dl) {
                tot[dk2*7+dl] += ry[dk2] + rx[dl];
                mx = fmaxf(mx, tot[dk2*7+dl]);
            }
        float sum = 0.f;
        #pragma unroll
        for (int i = 0; i < KK; ++i) { float e = __expf(tot[i]-mx); tot[i]=e; sum += e; }
        float inv = 1.f/sum;
        float* base = ws + ATTNOFF + ((size_t)(b*HH + h)*64)*WW + w;
        #pragma unroll
        for (int i = 0; i < KK; ++i) base[(size_t)i*WW] = tot[i]*inv;
    }
}

// ---- PV v3: h-strip LDS-staged v (kills the 7x dk-halo re-read) ----
// block = (b, 4-row strip hs, 16-ch group cg); 768 blocks x 192 threads.
// vtile [chq][10 rows][56 wslot] f32x4 = 35.8 KB, zero-padded halo.
// attn row -> 49 registers (issued before staging; latency overlaps).
__global__ __launch_bounds__(192) void pv_kernel(
    const float* __restrict__ bias,
    const float* __restrict__ ws,
    float* __restrict__ out)
{
    const float* vbuf = ws + (size_t)2*QSZ;
    const float* attn = ws + ATTNOFF;
    __shared__ f32x4 vtile[4*10*56];          // 35840 B

    const int bid = blockIdx.x;
    const int cg = bid & 15;                  // 16-channel group
    const int hs = (bid >> 4) % 12;           // 4-row strip
    const int b  = bid / (16*12);
    const int h0 = hs*4;

    const int t = threadIdx.x;
    const int hl = t / 48, w = t % 48;
    const int h = h0 + hl;

    // attn -> registers (coalesced across w); overlaps v staging below
    const float* ab = attn + ((size_t)(b*HH + h)*64)*WW + w;
    float a[KK];
    #pragma unroll
    for (int i = 0; i < KK; ++i) a[i] = ab[(size_t)i*WW];

    // stage v tile (chq-major: ds_read stride 16B -> conflict-free)
    for (int s = t; s < 4*10*56; s += 192) {
        int chq = s / 560;
        int rem = s - chq*560;
        int row = rem / 56, wslot = rem - row*56;
        int gr = h0 + row - 3, gc = wslot - 3;
        f32x4 v = (f32x4){0.f,0.f,0.f,0.f};
        if (gr >= 0 && gr < HH && gc >= 0 && gc < WW)
            v = *(const f32x4*)(vbuf + (((size_t)b*64 + cg*4 + chq)*HWHW + gr*WW + gc)*4);
        vtile[s] = v;
    }
    __syncthreads();

    #pragma unroll
    for (int chq = 0; chq < 4; ++chq) {
        const float4 b4 = *(const float4*)(bias + cg*16 + chq*4);
        f32x4 acc = (f32x4){b4.x, b4.y, b4.z, b4.w};
        #pragma unroll
        for (int dk = 0; dk < 7; ++dk) {
            const f32x4* vrow = &vtile[(chq*10 + hl + dk)*56 + w];
            #pragma unroll
            for (int dl = 0; dl < 7; ++dl)
                acc += vrow[dl] * a[dk*7+dl];
        }
        float* ob = out + ((size_t)(b*CC + cg*16 + chq*4))*HWHW + (size_t)h*WW + w;
        #pragma unroll
        for (int c = 0; c < 4; ++c) ob[(size_t)c*HWHW] = acc[c];
    }
}

extern "C" void kernel_launch(void* const* d_in, const int* in_sizes, int n_in,
                              void* d_out, int out_size, void* d_ws, size_t ws_size,
                              hipStream_t stream) {
    const float* x    = (const float*)d_in[0];
    const float* wq   = (const float*)d_in[1];
    const float* wk   = (const float*)d_in[2];
    const float* wv   = (const float*)d_in[3];
    const float* bias = (const float*)d_in[4];
    const float* relx = (const float*)d_in[5];
    const float* rely = (const float*)d_in[6];
    float* ws  = (float*)d_ws;
    float* out = (float*)d_out;
    unsigned short* xt = (unsigned short*)d_out;
    unsigned short* wt = (unsigned short*)(ws + WTOFF);

    prep_kernel<<<dim3(577), dim3(256), 0, stream>>>(x, wq, wk, wv, relx, rely, xt, wt, ws);
    proj_gemm_kernel<<<dim3(3, 144), dim3(512), 0, stream>>>(xt, wt, ws);
    scores2_kernel<<<dim3(BB*HH), dim3(512), 0, stream>>>(ws);
    pv_kernel<<<dim3(BB*12*16), dim3(192), 0, stream>>>(bias, ws, out);
}